// Round 12
// baseline (69.913 us; speedup 1.0000x reference)
//
#include <hip/hip_runtime.h>
#include <math.h>

#define S_LEN    16
#define NTOK     64     // tokens, m = s*4 + b
#define DMODEL   512
#define XB_COLS  2176   // x part (2048) + B part (128); z and C parts are dead code
#define ZX_COLS  2240   // XB_COLS + 64 dt columns
#define NCLASS   2513
#define FEATDIM  4096
#define PD_STRIDE 2516  // padded class stride (mult of 4 -> float4-aligned rows)

typedef float f4v __attribute__((ext_vector_type(4)));

// ---------------- k_fpart: in_proj partials, standard GEMM tile ------------------
// (unchanged from round 11 — conflict-free, measured-good)
__global__ __launch_bounds__(256) void k_fpart(const float* __restrict__ X,
                                               const float* __restrict__ W,
                                               float* __restrict__ partF) {
    const int tid = threadIdx.x;
    const int kf  = blockIdx.y;               // 64-k chunk
    const int jb  = blockIdx.x * 64;          // 2240 = 35*64 exact
    const int k0  = kf * 64;

    __shared__ float A[64][64];               // [k][token]
    __shared__ float B[64][64];               // [k][col]

    {
        const int t  = tid >> 2;              // 0..63 (token / col slot)
        const int kq = tid & 3;
        const int xrow = (t & 3) * 16 + (t >> 2);   // inputs row for token t
        const int e = (jb + t < XB_COLS) ? (2048 + jb + t) : (2176 + jb + t);
#pragma unroll
        for (int q = 0; q < 4; ++q) {
            const int kk = kq * 16 + q * 4;
            const float4 va = *reinterpret_cast<const float4*>(
                X + (size_t)xrow * DMODEL + k0 + kk);
            A[kk + 0][t] = va.x; A[kk + 1][t] = va.y;
            A[kk + 2][t] = va.z; A[kk + 3][t] = va.w;
            const float4 vb = *reinterpret_cast<const float4*>(
                W + (size_t)e * DMODEL + k0 + kk);
            B[kk + 0][t] = vb.x; B[kk + 1][t] = vb.y;
            B[kk + 2][t] = vb.z; B[kk + 3][t] = vb.w;
        }
    }
    __syncthreads();

    const int ti = tid >> 4;     // token quad 0..15
    const int ci = tid & 15;     // col quad 0..15
    float acc[4][4] = {{0.f}};
#pragma unroll 4
    for (int k = 0; k < 64; ++k) {
        const f4v a = *reinterpret_cast<const f4v*>(&A[k][ti * 4]);
        const f4v b = *reinterpret_cast<const f4v*>(&B[k][ci * 4]);
#pragma unroll
        for (int j = 0; j < 4; ++j)
#pragma unroll
            for (int l = 0; l < 4; ++l)
                acc[j][l] += a[j] * b[l];
    }
#pragma unroll
    for (int l = 0; l < 4; ++l) {
        f4v s; s[0] = acc[0][l]; s[1] = acc[1][l]; s[2] = acc[2][l]; s[3] = acc[3][l];
        *reinterpret_cast<f4v*>(
            partF + ((size_t)kf * ZX_COLS + jb + ci * 4 + l) * 64 + ti * 4) = s;
    }
}

// ---------------- k_fepi: reduce partials + conv/silu + dt/dA ---------------------
__global__ __launch_bounds__(256) void k_fepi(const float* __restrict__ partF, int KF,
                                              const float* __restrict__ conv_w,
                                              const float* __restrict__ conv_b,
                                              const float* __restrict__ dt_bias,
                                              const float* __restrict__ A_log,
                                              float* __restrict__ u,
                                              float* __restrict__ aArr,
                                              float* __restrict__ dArr) {
    const int lane = threadIdx.x & 63;                 // token m
    const int j    = blockIdx.x * 4 + (threadIdx.x >> 6);
    float acc = 0.f;
    for (int kf = 0; kf < KF; ++kf)
        acc += partF[((size_t)kf * ZX_COLS + j) * 64 + lane];

    if (j < XB_COLS) {
        const float4 cwv = *reinterpret_cast<const float4*>(conv_w + j * 4);
        const float cb = conv_b[j];
        float wk[4];
        wk[0] = cwv.w;                  // cw[:,0] = conv_w[:,3]
        wk[1] = wk[0] + cwv.z;
        wk[2] = wk[1] + cwv.y;
        wk[3] = wk[2] + cwv.x;
#pragma unroll
        for (int k = 0; k < 4; ++k) {
            const float v = acc * wk[k] + cb;
            u[((size_t)k * NTOK + lane) * XB_COLS + j] = v / (1.f + expf(-v));
        }
    } else {
        const int h = j - XB_COLS;
        const float x = acc + dt_bias[h];
        const float d = (x > 20.f) ? x : log1pf(expf(x));
        dArr[lane * 64 + h] = d;
        aArr[lane * 64 + h] = expf(-d * expf(A_log[h]));
    }
}

// ---------------- k_feats: collapsed SSM -> feats ROW-major [r][4096] -------------
__global__ __launch_bounds__(256) void k_feats(const float* __restrict__ u,
                                               const float* __restrict__ aArr,
                                               const float* __restrict__ dArr,
                                               float* __restrict__ feats) {
    const int t = blockIdx.x >> 2;
    const int b = blockIdx.x & 3;
    const int tid = threadIdx.x;
    const int K = 16 - t;          // unroll updates k = 0..K
    const int nvec = t + 5;        // (t+1) scan vectors + 4 unroll vectors

    __shared__ float q[16][64];
    __shared__ float cu[4][64];
    __shared__ float WV[20][32];
    __shared__ float Bv[20][128];

    if (tid < 64) {
        const int h = tid;
        const int mt = t * 4 + b;
        const float a   = aArr[mt * 64 + h];
        const float dtv = dArr[mt * 64 + h];
        float p = 1.f;
        float c3 = 0.f, c2 = 0.f, c1 = 0.f, c0 = 0.f, cs = 0.f;
        for (int j = 0; j <= K + 1; ++j) {     // p = a^j at loop head
            if (j <= K - 3) c3 += p;
            if (j == K - 2) c2 = p;
            if (j == K - 1) c1 = p;
            if (j == K)     c0 = p;
            if (j == K + 1) cs = p;
            p *= a;
        }
        cu[0][h] = dtv * c0;
        cu[1][h] = dtv * c1;
        cu[2][h] = dtv * c2;
        cu[3][h] = dtv * c3;
        float prod = 1.f;
        for (int s = t; s >= 0; --s) {
            const int ms = s * 4 + b;
            q[s][h] = cs * prod * dArr[ms * 64 + h];
            prod *= aArr[ms * 64 + h];
        }
    }
    __syncthreads();

    {   // head-reduced x vectors (32 wide each)
        const int i = tid & 31;
        const int vs = tid >> 5;
        for (int v = vs; v < nvec; v += 8) {
            float acc = 0.f;
            if (v <= t) {
                const float* base = u + (size_t)(v * 4 + b) * XB_COLS;
                for (int h = 0; h < 64; ++h) acc += q[v][h] * base[h * 32 + i];
            } else {
                const int kk = v - t - 1;
                const float* base = u + ((size_t)kk * NTOK + t * 4 + b) * XB_COLS;
                for (int h = 0; h < 64; ++h) acc += cu[kk][h] * base[h * 32 + i];
            }
            WV[v][i] = acc;
        }
    }
    for (int x = tid; x < nvec * 128; x += 256) {
        const int v = x >> 7, n = x & 127;
        size_t src;
        if (v <= t) src = (size_t)(v * 4 + b) * XB_COLS + 2048 + n;
        else        src = ((size_t)(v - t - 1) * NTOK + t * 4 + b) * XB_COLS + 2048 + n;
        Bv[v][n] = u[src];
    }
    __syncthreads();

    {   // rank-nvec outer products -> feats[r][4096] row-major
        const int i  = tid >> 3;            // headdim index 0..31
        const int n0 = (tid & 7) * 16;      // state offset
        const int r  = b * 16 + t;          // output row
        float acc[16];
#pragma unroll
        for (int nn = 0; nn < 16; ++nn) acc[nn] = 0.f;
        for (int v = 0; v < nvec; ++v) {
            const float wvv = WV[v][i];
#pragma unroll
            for (int nn = 0; nn < 16; ++nn) acc[nn] += wvv * Bv[v][n0 + nn];
        }
        float* dst = feats + (size_t)r * FEATDIM + i * 128 + n0;
#pragma unroll
        for (int qq = 0; qq < 4; ++qq) {
            float4 v4;
            v4.x = acc[qq * 4 + 0] * (1.f / 64.f);
            v4.y = acc[qq * 4 + 1] * (1.f / 64.f);
            v4.z = acc[qq * 4 + 2] * (1.f / 64.f);
            v4.w = acc[qq * 4 + 3] * (1.f / 64.f);
            *reinterpret_cast<float4*>(dst + qq * 4) = v4;
        }
    }
}

// ---------------- k_cls: classifier GEMM, 1-wave blocks, micro 8x8 ----------------
// grid (40, KC) x 64 thr. Block: 64 tokens x 64 classes x (4096/KC)-k chunk.
// Per 64-k subtile: stage A[64k][64t] + B[64k][64c] (4x4 reg-transpose, b128
// writes); per k: 4 bank-sweep broadcast ds_read_b128 feed 64 FMAs.
// Thread (ti=tid>>3, ci=tid&7): tokens {ti*4..+3, 32+ti*4..+3},
//                               classes {ci*4..+3, 32+ci*4..+3}.
__global__ __launch_bounds__(64) void k_cls(const float* __restrict__ feats,
                                            const float* __restrict__ Wc,
                                            float* __restrict__ partialD) {
    const int tid   = threadIdx.x;
    const int ks    = blockIdx.y;
    const int cls0  = blockIdx.x * 64;           // 40*64 = 2560 >= 2513
    const int chunk = FEATDIM / gridDim.y;
    const int nsub  = chunk / 64;

    __shared__ float A[64][64];                  // [k][token]
    __shared__ float B[64][64];                  // [k][class]

    const int ti = tid >> 3;                     // 0..7
    const int ci = tid & 7;                      // 0..7
    const int sq = tid & 15;                     // stage: token/class quad
    const int sk = tid >> 4;                     // stage: k-quad base (0..3)

    float acc[8][8] = {{0.f}};

    for (int st = 0; st < nsub; ++st) {
        const int k0 = ks * chunk + st * 64;
        __syncthreads();                         // protect A/B reuse (1-wave: cheap)
#pragma unroll
        for (int j = 0; j < 4; ++j) {
            const int kslot = sk + j * 4;        // 0..15
            // A: feats rows = tokens
            float4 va[4];
#pragma unroll
            for (int r = 0; r < 4; ++r)
                va[r] = *reinterpret_cast<const float4*>(
                    feats + (size_t)(sq * 4 + r) * FEATDIM + k0 + kslot * 4);
#pragma unroll
            for (int s = 0; s < 4; ++s) {
                f4v w; w[0] = (&va[0].x)[s]; w[1] = (&va[1].x)[s];
                       w[2] = (&va[2].x)[s]; w[3] = (&va[3].x)[s];
                *reinterpret_cast<f4v*>(&A[kslot * 4 + s][sq * 4]) = w;
            }
            // B: Wc rows = classes (clamped at tail)
            float4 vb[4];
#pragma unroll
            for (int r = 0; r < 4; ++r) {
                int cr = cls0 + sq * 4 + r; if (cr > NCLASS - 1) cr = NCLASS - 1;
                vb[r] = *reinterpret_cast<const float4*>(
                    Wc + (size_t)cr * FEATDIM + k0 + kslot * 4);
            }
#pragma unroll
            for (int s = 0; s < 4; ++s) {
                f4v w; w[0] = (&vb[0].x)[s]; w[1] = (&vb[1].x)[s];
                       w[2] = (&vb[2].x)[s]; w[3] = (&vb[3].x)[s];
                *reinterpret_cast<f4v*>(&B[kslot * 4 + s][sq * 4]) = w;
            }
        }
        __syncthreads();

#pragma unroll 8
        for (int k = 0; k < 64; ++k) {
            const f4v a0 = *reinterpret_cast<const f4v*>(&A[k][ti * 4]);
            const f4v a1 = *reinterpret_cast<const f4v*>(&A[k][32 + ti * 4]);
            const f4v b0 = *reinterpret_cast<const f4v*>(&B[k][ci * 4]);
            const f4v b1 = *reinterpret_cast<const f4v*>(&B[k][32 + ci * 4]);
#pragma unroll
            for (int j = 0; j < 4; ++j) {
#pragma unroll
                for (int l = 0; l < 4; ++l) {
                    acc[j][l]         += a0[j] * b0[l];
                    acc[j][l + 4]     += a0[j] * b1[l];
                    acc[j + 4][l]     += a1[j] * b0[l];
                    acc[j + 4][l + 4] += a1[j] * b1[l];
                }
            }
        }
    }

    const size_t obase = (size_t)ks * (NTOK * PD_STRIDE);
#pragma unroll
    for (int ta = 0; ta < 2; ++ta) {
#pragma unroll
        for (int j = 0; j < 4; ++j) {
            const int row = ta * 32 + ti * 4 + j;
#pragma unroll
            for (int cb = 0; cb < 2; ++cb) {
                const int c = cls0 + cb * 32 + ci * 4;
                f4v s;
#pragma unroll
                for (int l = 0; l < 4; ++l) s[l] = acc[ta * 4 + j][cb * 4 + l];
                float* dst = partialD + obase + (size_t)row * PD_STRIDE + c;
                if (c + 3 < NCLASS) {
                    *reinterpret_cast<f4v*>(dst) = s;
                } else {
#pragma unroll
                    for (int l = 0; l < 4; ++l)
                        if (c + l < NCLASS) dst[l] = s[l];
                }
            }
        }
    }
}

// ---------------- k_out: reduce split-K partials + bias -> out --------------------
__global__ void k_out(const float* __restrict__ partialD, const float* __restrict__ cls_b,
                      float* __restrict__ out, int KC) {
    const int bx = blockIdx.x;                   // 640 = 64 rows * 10 c-chunks
    const int r  = bx / 10;
    const int c  = (bx % 10) * 256 + threadIdx.x;
    if (c >= NCLASS) return;
    float s = cls_b[c];
    for (int ks = 0; ks < KC; ++ks)
        s += partialD[(size_t)ks * (NTOK * PD_STRIDE) + (size_t)r * PD_STRIDE + c];
    out[(size_t)r * NCLASS + c] = s;
}

// ------------------------------------------------------------------------------
extern "C" void kernel_launch(void* const* d_in, const int* in_sizes, int n_in,
                              void* d_out, int out_size, void* d_ws, size_t ws_size,
                              hipStream_t stream) {
    const float* inputs  = (const float*)d_in[0];
    const float* in_proj = (const float*)d_in[1];
    const float* conv_w  = (const float*)d_in[2];
    const float* conv_b  = (const float*)d_in[3];
    const float* dt_bias = (const float*)d_in[4];
    const float* A_log   = (const float*)d_in[5];
    const float* cls_w   = (const float*)d_in[6];
    const float* cls_b   = (const float*)d_in[7];
    float* out = (float*)d_out;

    float* ws = (float*)d_ws;
    float* aArr    = ws;               //   4096
    float* dArr    = ws + 4096;        //   4096
    float* feats   = ws + 8192;        // 262144 (row-major [r][4096])
    float* scr     = ws + 270336;
    float* u       = scr;              // 557056 (dead after k_feats)
    float* partF   = scr + 557056;     // 8*2240*64 = 1146880 (dead after k_fepi)
    float* partialD = scr;             // KC*64*2516 (written after k_feats)

    // tiers: bytes = (270336 + max(1703936, KC*64*2516)) * 4
    //   KC=16 -> 11,386,880 (proven in round 11)   KC=8 -> 7,897,088 (proven tier)
    int KC;
    if (ws_size >= 11386880u) KC = 16;
    else                      KC = 8;

    k_fpart <<<dim3(35, 8), 256, 0, stream>>>(inputs, in_proj, partF);
    k_fepi  <<<560, 256, 0, stream>>>(partF, 8, conv_w, conv_b, dt_bias, A_log,
                                      u, aArr, dArr);
    k_feats <<<64, 256, 0, stream>>>(u, aArr, dArr, feats);
    k_cls   <<<dim3(40, KC), 64, 0, stream>>>(feats, cls_w, partialD);
    k_out   <<<640, 256, 0, stream>>>(partialD, cls_b, out, KC);
}